// Round 1
// baseline (198.213 us; speedup 1.0000x reference)
//
#include <hip/hip_runtime.h>
#include <math.h>

#define NB 512
#define NS 64
#define ND 2048
#define NP 1024   // ND/2

// ws layout (float offsets): M0, M1, Qt, R, W, partial, cnt
#define OFF_M0   0
#define OFF_M1   131072
#define OFF_QT   262144   // 1024*64*3 = 196608
#define OFF_R    458752   // 64*2048  = 131072
#define OFF_W    589824   // 64*64    = 4096
#define OFF_PART 593920   // 4*512*64 = 131072
#define OFF_CNT  724992   // 64 ints

// ---------------- threefry2x32 (exact jax semantics, key=(0,42)) -------------
__device__ __forceinline__ unsigned rotl32(unsigned x, int d) {
    return (x << d) | (x >> (32 - d));
}

__device__ __forceinline__ void threefry2x32(unsigned k0, unsigned k1,
                                             unsigned& x0, unsigned& x1) {
    const unsigned ks0 = k0, ks1 = k1, ks2 = k0 ^ k1 ^ 0x1BD11BDAu;
    const int r0[4] = {13, 15, 26, 6};
    const int r1[4] = {17, 29, 16, 24};
    x0 += ks0; x1 += ks1;
#pragma unroll
    for (int i = 0; i < 4; ++i) { x0 += x1; x1 = rotl32(x1, r0[i]); x1 ^= x0; }
    x0 += ks1; x1 += ks2 + 1u;
#pragma unroll
    for (int i = 0; i < 4; ++i) { x0 += x1; x1 = rotl32(x1, r1[i]); x1 ^= x0; }
    x0 += ks2; x1 += ks0 + 2u;
#pragma unroll
    for (int i = 0; i < 4; ++i) { x0 += x1; x1 = rotl32(x1, r0[i]); x1 ^= x0; }
    x0 += ks0; x1 += ks1 + 3u;
#pragma unroll
    for (int i = 0; i < 4; ++i) { x0 += x1; x1 = rotl32(x1, r1[i]); x1 ^= x0; }
    x0 += ks1; x1 += ks2 + 4u;
#pragma unroll
    for (int i = 0; i < 4; ++i) { x0 += x1; x1 = rotl32(x1, r0[i]); x1 ^= x0; }
    x0 += ks2; x1 += ks0 + 5u;
}

// ---------------- K0: per-row norm + softmax(E row) + R = real_amp -----------
// 64 blocks x 256 threads; block t handles amp row t + E row t.
// Kills the 256x-redundant norm reads and 64x-redundant sin/cos of old k_MQ.
// Norm reduce bitwise-replicates the old 16-thread pattern.
__global__ void __launch_bounds__(256)
k_pre(const float* __restrict__ amp, const float* __restrict__ ph,
      const float* __restrict__ E, float* __restrict__ R,
      float* __restrict__ W, int* __restrict__ cnt) {
    __shared__ float in_sh;
    const int t = blockIdx.x;
    const int tid = threadIdx.x;

    if (t == 0 && tid < NS) cnt[tid] = 0;   // zero last-block counters (graph-replay safe)

    if (tid < 16) {  // wave 0: norm of amp row t (exact old summation order)
        const float4* a4 = (const float4*)(amp + t * ND);
        float acc = 0.f;
#pragma unroll 8
        for (int i = 0; i < 32; ++i) {
            float4 v = a4[tid + 16 * i];
            acc += v.x * v.x + v.y * v.y + v.z * v.z + v.w * v.w;
        }
        acc += __shfl_down(acc, 8, 16);
        acc += __shfl_down(acc, 4, 16);
        acc += __shfl_down(acc, 2, 16);
        acc += __shfl_down(acc, 1, 16);
        if (tid == 0) in_sh = 1.0f / sqrtf(acc);
    }
    if (tid >= 64 && tid < 128) {  // wave 1: softmax of E row t (exact old pattern)
        const int s = tid - 64;
        float e = E[t * NS + s];
        float m = e;
        for (int off = 32; off; off >>= 1) m = fmaxf(m, __shfl_down(m, off));
        m = __shfl(m, 0);
        float ex = expf(e - m);
        float sum = ex;
        for (int off = 32; off; off >>= 1) sum += __shfl_down(sum, off);
        sum = __shfl(sum, 0);
        W[t * NS + s] = ex / sum;
    }
    __syncthreads();

    const float in = in_sh;
    const float2* a2 = (const float2*)(amp + t * ND);
    const float2* p2 = (const float2*)(ph + t * ND);
    float2* r2 = (float2*)(R + t * ND);
#pragma unroll
    for (int k = 0; k < 4; ++k) {
        const int i = tid + 256 * k;
        float2 av = a2[i], pv = p2[i];
        float2 rv;
        rv.x = av.x * in * (__cosf(pv.x) + __sinf(pv.x));  // exact old expression
        rv.y = av.y * in * (__cosf(pv.y) + __sinf(pv.y));
        r2[i] = rv;
    }
}

// ---------------- K1: M0/M1/Qt from precomputed R, W ------------------------
// 256 blocks x 1024 threads: srow = blk>>2, pair chunk = (blk&3)*256.
// t-loop rotated by srow so the 64 blocks sharing a p-chunk hit different
// R cache lines at any instant (de-camps L2 channels).
__global__ void __launch_bounds__(1024)
k_MQ(const float* __restrict__ R, const float* __restrict__ W,
     const float* __restrict__ G,
     float* __restrict__ M0, float* __restrict__ M1, float* __restrict__ Qt) {
    __shared__ float W_l[NS];
    __shared__ float Gl[NS * 4];
    __shared__ float4 part4[4][256];   // per-tgroup partial (a0,a1,b0,b1)
    const int blk = blockIdx.x;
    const int tid = threadIdx.x;
    const int srow = blk >> 2;

    if (tid < NS) W_l[tid] = W[srow * NS + tid];
    if (tid >= 256 && tid < 256 + NS * 4) Gl[tid - 256] = G[tid - 256];
    __syncthreads();

    {
        const int pi = tid & 255;
        const int tg = tid >> 8;           // 0..3
        const int p = ((blk & 3) << 8) + pi;
        const int t0 = tg << 4;
        const float2* r2 = (const float2*)R;
        float a0 = 0.f, a1 = 0.f, b0 = 0.f, b1 = 0.f;
#pragma unroll 4
        for (int j = 0; j < 16; ++j) {
            const int t = t0 + ((j + srow) & 15);   // skewed visit order
            float2 rv = r2[t * NP + p];
            float w = W_l[t];
            float wr0 = w * rv.x, wr1 = w * rv.y;
            a0 += wr0 * Gl[4 * t + 0];
            b0 += wr0 * Gl[4 * t + 2];
            a1 += wr1 * Gl[4 * t + 1];
            b1 += wr1 * Gl[4 * t + 3];
        }
        part4[tg][pi] = make_float4(a0, a1, b0, b1);
    }
    __syncthreads();

    if (tid < 256) {  // combine 4 partials (fixed order), write M0/M1/Qt
        const int p = ((blk & 3) << 8) + tid;
        float4 s0 = part4[0][tid], s1 = part4[1][tid],
               s2 = part4[2][tid], s3 = part4[3][tid];
        float a0 = s0.x + s1.x + s2.x + s3.x;
        float a1 = s0.y + s1.y + s2.y + s3.y;
        float b0 = s0.z + s1.z + s2.z + s3.z;
        float b1 = s0.w + s1.w + s2.w + s3.w;
        float2 m0v = {a0, a1}, m1v = {b0, b1};
        ((float2*)(M0 + srow * ND))[p] = m0v;
        ((float2*)(M1 + srow * ND))[p] = m1v;
        float* qp = Qt + p * 192 + srow * 3;   // [p][s][3]
        qp[0] = a0 * a0 + a1 * a1;
        qp[1] = a0 * b0 + a1 * b1;
        qp[2] = b0 * b0 + b1 * b1;
    }
}

// ---------------- K2: partial logits (8 rows x 1/4 p-range) + last-block
//                      collapse + output. Qt traffic 201 MB -> 50 MB. ---------
// 256 blocks x 1024 threads: rg = blk>>2 (rows rg*8..+8), pc = blk&3
// (pairs pc*256..+256). p-loop rotated by rg to de-camp L2 channels.
// 4 blocks per row-group publish deterministic partial slots; the last one
// (device-scope counter) reduces in fixed order, does exact gumbel argmax,
// and writes the 8 output rows.
__global__ void __launch_bounds__(1024)
k_log(const float* __restrict__ x, const float* __restrict__ Qt,
      const float* __restrict__ M0, const float* __restrict__ M1,
      float* __restrict__ pglob, int* __restrict__ cnt,
      float* __restrict__ out) {
    __shared__ float4 xq[8][256];        // 32 KB: (x0^2, 2*x0*x1, x1^2, 0) per pair
    __shared__ float part[16][8][64];    // 32 KB
    __shared__ int o_sh[8];
    __shared__ int last_sh;
    const int blk = blockIdx.x;
    const int tid = threadIdx.x;
    const int rg = blk >> 2, pc = blk & 3;
    const int r0 = rg * 8;

    {   // stage x chunk in quadratic form (coalesced float4)
        const int r = tid >> 7, i = tid & 127;
        float4 v = ((const float4*)(x + (r0 + r) * ND + pc * 512))[i];
        float4 q0, q1;
        q0.x = v.x * v.x; q0.y = 2.f * v.x * v.y; q0.z = v.y * v.y; q0.w = 0.f;
        q1.x = v.z * v.z; q1.y = 2.f * v.z * v.w; q1.z = v.w * v.w; q1.w = 0.f;
        xq[r][2 * i] = q0;
        xq[r][2 * i + 1] = q1;
    }
    __syncthreads();

    const int w = tid >> 6, s = tid & 63;
    {
        float acc[8] = {0.f, 0.f, 0.f, 0.f, 0.f, 0.f, 0.f, 0.f};
        const float* qbase = Qt + (pc * 256) * 192 + s * 3;
#pragma unroll 4
        for (int j = 0; j < 16; ++j) {
            const int pl = (w << 4) + ((j + rg) & 15);   // skewed visit order
            const float* qp = qbase + pl * 192;
            float q0 = qp[0], q1 = qp[1], q2 = qp[2];
#pragma unroll
            for (int r = 0; r < 8; ++r) {
                float4 xv = xq[r][pl];                   // LDS broadcast
                acc[r] += xv.x * q0 + xv.y * q1 + xv.z * q2;
            }
        }
#pragma unroll
        for (int r = 0; r < 8; ++r) part[w][r][s] = acc[r];
    }
    __syncthreads();

    if (tid < 512) {  // cross-wave reduce (fixed order), publish partial slot
        const int rr = tid >> 6;
        float l = 0.f;
#pragma unroll
        for (int k = 0; k < 16; ++k) l += part[k][rr][s];
        pglob[(pc * NB + r0 + rr) * NS + s] = l;
    }
    __threadfence();       // device-scope release of partial stores
    __syncthreads();
    if (tid == 0) {
        int prev = atomicAdd(cnt + rg, 1);
        last_sh = (prev == 3);
    }
    __syncthreads();
    if (!last_sh) return;
    __threadfence();       // acquire before reading peers' partials

    if (tid < 512) {  // reduce 4 slots (fixed order) + exact jax categorical
        const int w2 = tid >> 6;
        const int row = r0 + w2;
        float l = 0.f;
#pragma unroll
        for (int c = 0; c < 4; ++c) l += pglob[(c * NB + row) * NS + s];
        unsigned n = (unsigned)(row * NS + s);
        unsigned t0u = 0u, t1u = n;
        threefry2x32(0u, 42u, t0u, t1u);
        unsigned bits = t0u ^ t1u;
        float u = (float)(bits >> 9) * (1.0f / 8388608.0f);
        u = fmaxf(u, 1.17549435e-38f);
        float g = -logf(-logf(u));
        float best = l + g;
        int bi = s;
        for (int off = 32; off; off >>= 1) {
            float ov = __shfl_down(best, off);
            int oi = __shfl_down(bi, off);
            if (ov > best || (ov == best && oi < bi)) { best = ov; bi = oi; }
        }
        if (s == 0) o_sh[w2] = bi;
    }
    __syncthreads();

#pragma unroll
    for (int r = 0; r < 8; ++r) {  // output: thread = pair, coalesced
        const int o = o_sh[r];
        float2 xv = ((const float2*)(x + (r0 + r) * ND))[tid];
        float2 m0 = ((const float2*)(M0 + o * ND))[tid];
        float2 m1 = ((const float2*)(M1 + o * ND))[tid];
        float2 rr;
        rr.x = xv.x * m0.x + xv.y * m1.x;
        rr.y = xv.x * m0.y + xv.y * m1.y;
        ((float2*)(out + (r0 + r) * ND))[tid] = rr;
    }
}

extern "C" void kernel_launch(void* const* d_in, const int* in_sizes, int n_in,
                              void* d_out, int out_size, void* d_ws, size_t ws_size,
                              hipStream_t stream) {
    const float* x   = (const float*)d_in[0];  // [512,2048]
    const float* amp = (const float*)d_in[1];  // [64,2048]
    const float* ph  = (const float*)d_in[2];  // [64,2048]
    const float* G   = (const float*)d_in[3];  // [64,2,2]
    const float* E   = (const float*)d_in[4];  // [64,64]
    float* out = (float*)d_out;
    float* ws = (float*)d_ws;

    float* M0 = ws + OFF_M0;
    float* M1 = ws + OFF_M1;
    float* Qt = ws + OFF_QT;
    float* R  = ws + OFF_R;
    float* W  = ws + OFF_W;
    float* pp = ws + OFF_PART;
    int*  cnt = (int*)(ws + OFF_CNT);

    k_pre<<<64, 256, 0, stream>>>(amp, ph, E, R, W, cnt);
    k_MQ <<<256, 1024, 0, stream>>>(R, W, G, M0, M1, Qt);
    k_log<<<256, 1024, 0, stream>>>(x, Qt, M0, M1, pp, cnt, out);
}

// Round 2
// 84.878 us; speedup vs baseline: 2.3353x; 2.3353x over previous
//
#include <hip/hip_runtime.h>
#include <math.h>

#define NB 512
#define NS 64
#define ND 2048
#define NP 1024   // ND/2

// ws layout (float offsets): M0, M1, Qt, R, W, pglob
#define OFF_M0   0
#define OFF_M1   131072
#define OFF_QT   262144   // 1024*64*3 = 196608
#define OFF_R    458752   // 64*2048  = 131072
#define OFF_W    589824   // 64*64    = 4096
#define OFF_PART 593920   // 4*512*64 = 131072

// ---------------- threefry2x32 (exact jax semantics, key=(0,42)) -------------
__device__ __forceinline__ unsigned rotl32(unsigned x, int d) {
    return (x << d) | (x >> (32 - d));
}

__device__ __forceinline__ void threefry2x32(unsigned k0, unsigned k1,
                                             unsigned& x0, unsigned& x1) {
    const unsigned ks0 = k0, ks1 = k1, ks2 = k0 ^ k1 ^ 0x1BD11BDAu;
    const int r0[4] = {13, 15, 26, 6};
    const int r1[4] = {17, 29, 16, 24};
    x0 += ks0; x1 += ks1;
#pragma unroll
    for (int i = 0; i < 4; ++i) { x0 += x1; x1 = rotl32(x1, r0[i]); x1 ^= x0; }
    x0 += ks1; x1 += ks2 + 1u;
#pragma unroll
    for (int i = 0; i < 4; ++i) { x0 += x1; x1 = rotl32(x1, r1[i]); x1 ^= x0; }
    x0 += ks2; x1 += ks0 + 2u;
#pragma unroll
    for (int i = 0; i < 4; ++i) { x0 += x1; x1 = rotl32(x1, r0[i]); x1 ^= x0; }
    x0 += ks0; x1 += ks1 + 3u;
#pragma unroll
    for (int i = 0; i < 4; ++i) { x0 += x1; x1 = rotl32(x1, r1[i]); x1 ^= x0; }
    x0 += ks1; x1 += ks2 + 4u;
#pragma unroll
    for (int i = 0; i < 4; ++i) { x0 += x1; x1 = rotl32(x1, r0[i]); x1 ^= x0; }
    x0 += ks2; x1 += ks0 + 5u;
}

// ---------------- K0: per-row norm + softmax(E row) + R = real_amp -----------
// 64 blocks x 256 threads; block t handles amp row t + E row t.
// Norm reduce bitwise-replicates the original 16-thread pattern.
__global__ void __launch_bounds__(256)
k_pre(const float* __restrict__ amp, const float* __restrict__ ph,
      const float* __restrict__ E, float* __restrict__ R,
      float* __restrict__ W) {
    __shared__ float in_sh;
    const int t = blockIdx.x;
    const int tid = threadIdx.x;

    if (tid < 16) {  // wave 0: norm of amp row t (exact old summation order)
        const float4* a4 = (const float4*)(amp + t * ND);
        float acc = 0.f;
#pragma unroll 8
        for (int i = 0; i < 32; ++i) {
            float4 v = a4[tid + 16 * i];
            acc += v.x * v.x + v.y * v.y + v.z * v.z + v.w * v.w;
        }
        acc += __shfl_down(acc, 8, 16);
        acc += __shfl_down(acc, 4, 16);
        acc += __shfl_down(acc, 2, 16);
        acc += __shfl_down(acc, 1, 16);
        if (tid == 0) in_sh = 1.0f / sqrtf(acc);
    }
    if (tid >= 64 && tid < 128) {  // wave 1: softmax of E row t (exact old pattern)
        const int s = tid - 64;
        float e = E[t * NS + s];
        float m = e;
        for (int off = 32; off; off >>= 1) m = fmaxf(m, __shfl_down(m, off));
        m = __shfl(m, 0);
        float ex = expf(e - m);
        float sum = ex;
        for (int off = 32; off; off >>= 1) sum += __shfl_down(sum, off);
        sum = __shfl(sum, 0);
        W[t * NS + s] = ex / sum;
    }
    __syncthreads();

    const float in = in_sh;
    const float2* a2 = (const float2*)(amp + t * ND);
    const float2* p2 = (const float2*)(ph + t * ND);
    float2* r2 = (float2*)(R + t * ND);
#pragma unroll
    for (int k = 0; k < 4; ++k) {
        const int i = tid + 256 * k;
        float2 av = a2[i], pv = p2[i];
        float2 rv;
        rv.x = av.x * in * (__cosf(pv.x) + __sinf(pv.x));  // exact old expression
        rv.y = av.y * in * (__cosf(pv.y) + __sinf(pv.y));
        r2[i] = rv;
    }
}

// ---------------- K1: M0/M1/Qt from precomputed R, W ------------------------
// 256 blocks x 1024 threads: srow = blk>>2, pair chunk = (blk&3)*256.
// t-loop rotated by srow so the 64 blocks sharing a p-chunk hit different
// R cache lines at any instant.
__global__ void __launch_bounds__(1024)
k_MQ(const float* __restrict__ R, const float* __restrict__ W,
     const float* __restrict__ G,
     float* __restrict__ M0, float* __restrict__ M1, float* __restrict__ Qt) {
    __shared__ float W_l[NS];
    __shared__ float Gl[NS * 4];
    __shared__ float4 part4[4][256];   // per-tgroup partial (a0,a1,b0,b1)
    const int blk = blockIdx.x;
    const int tid = threadIdx.x;
    const int srow = blk >> 2;

    if (tid < NS) W_l[tid] = W[srow * NS + tid];
    if (tid >= 256 && tid < 256 + NS * 4) Gl[tid - 256] = G[tid - 256];
    __syncthreads();

    {
        const int pi = tid & 255;
        const int tg = tid >> 8;           // 0..3
        const int p = ((blk & 3) << 8) + pi;
        const int t0 = tg << 4;
        const float2* r2 = (const float2*)R;
        float a0 = 0.f, a1 = 0.f, b0 = 0.f, b1 = 0.f;
#pragma unroll 4
        for (int j = 0; j < 16; ++j) {
            const int t = t0 + ((j + srow) & 15);   // skewed visit order
            float2 rv = r2[t * NP + p];
            float w = W_l[t];
            float wr0 = w * rv.x, wr1 = w * rv.y;
            a0 += wr0 * Gl[4 * t + 0];
            b0 += wr0 * Gl[4 * t + 2];
            a1 += wr1 * Gl[4 * t + 1];
            b1 += wr1 * Gl[4 * t + 3];
        }
        part4[tg][pi] = make_float4(a0, a1, b0, b1);
    }
    __syncthreads();

    if (tid < 256) {  // combine 4 partials (fixed order), write M0/M1/Qt
        const int p = ((blk & 3) << 8) + tid;
        float4 s0 = part4[0][tid], s1 = part4[1][tid],
               s2 = part4[2][tid], s3 = part4[3][tid];
        float a0 = s0.x + s1.x + s2.x + s3.x;
        float a1 = s0.y + s1.y + s2.y + s3.y;
        float b0 = s0.z + s1.z + s2.z + s3.z;
        float b1 = s0.w + s1.w + s2.w + s3.w;
        float2 m0v = {a0, a1}, m1v = {b0, b1};
        ((float2*)(M0 + srow * ND))[p] = m0v;
        ((float2*)(M1 + srow * ND))[p] = m1v;
        float* qp = Qt + p * 192 + srow * 3;   // [p][s][3]
        qp[0] = a0 * a0 + a1 * a1;
        qp[1] = a0 * b0 + a1 * b1;
        qp[2] = b0 * b0 + b1 * b1;
    }
}

// ---------------- K2a: partial logits (8 rows x 1/4 p-range) -----------------
// 256 blocks x 1024 threads: rg = blk>>2 (rows rg*8..+8), pc = blk&3
// (pairs pc*256..+256). p-loop rotated by rg to de-camp L2 channels.
// NO fences/atomics — the kernel boundary is the global barrier.
__global__ void __launch_bounds__(1024)
k_logA(const float* __restrict__ x, const float* __restrict__ Qt,
       float* __restrict__ pglob) {
    __shared__ float4 xq[8][256];        // 32 KB: (x0^2, 2*x0*x1, x1^2, 0) per pair
    __shared__ float part[16][8][64];    // 32 KB
    const int blk = blockIdx.x;
    const int tid = threadIdx.x;
    const int rg = blk >> 2, pc = blk & 3;
    const int r0 = rg * 8;

    {   // stage x chunk in quadratic form (coalesced float4)
        const int r = tid >> 7, i = tid & 127;
        float4 v = ((const float4*)(x + (r0 + r) * ND + pc * 512))[i];
        float4 q0, q1;
        q0.x = v.x * v.x; q0.y = 2.f * v.x * v.y; q0.z = v.y * v.y; q0.w = 0.f;
        q1.x = v.z * v.z; q1.y = 2.f * v.z * v.w; q1.z = v.w * v.w; q1.w = 0.f;
        xq[r][2 * i] = q0;
        xq[r][2 * i + 1] = q1;
    }
    __syncthreads();

    const int w = tid >> 6, s = tid & 63;
    {
        float acc[8] = {0.f, 0.f, 0.f, 0.f, 0.f, 0.f, 0.f, 0.f};
        const float* qbase = Qt + (pc * 256) * 192 + s * 3;
#pragma unroll 4
        for (int j = 0; j < 16; ++j) {
            const int pl = (w << 4) + ((j + rg) & 15);   // skewed visit order
            const float* qp = qbase + pl * 192;
            float q0 = qp[0], q1 = qp[1], q2 = qp[2];
#pragma unroll
            for (int r = 0; r < 8; ++r) {
                float4 xv = xq[r][pl];                   // LDS broadcast
                acc[r] += xv.x * q0 + xv.y * q1 + xv.z * q2;
            }
        }
#pragma unroll
        for (int r = 0; r < 8; ++r) part[w][r][s] = acc[r];
    }
    __syncthreads();

    if (tid < 512) {  // cross-wave reduce (fixed order), publish partial slot
        const int rr = tid >> 6;
        float l = 0.f;
#pragma unroll
        for (int k = 0; k < 16; ++k) l += part[k][rr][s];
        pglob[(pc * NB + r0 + rr) * NS + s] = l;
    }
}

// ---------------- K2b: final logits + collapse + output; 2 rows/block --------
// 256 blocks x 1024 threads. Reduce the 4 partial slots in FIXED order
// (bit-identical to the fused version), exact jax categorical, then the
// round-0-verified output gather.
__global__ void __launch_bounds__(1024)
k_logB(const float* __restrict__ x, const float* __restrict__ pglob,
       const float* __restrict__ M0, const float* __restrict__ M1,
       float* __restrict__ out) {
    __shared__ float2 xs[2 * NP];      // 16 KB: two x rows, as pairs
    __shared__ int o_sh[2];
    const int blk = blockIdx.x;
    const int tid = threadIdx.x;
    const int r0 = 2 * blk;

    // stage 2 x rows (coalesced float4: 1024 of them)
    ((float4*)xs)[tid] = ((const float4*)(x + r0 * ND))[tid];

    if (tid < 128) {  // waves 0-1: row r0+w2; reduce slots + gumbel-max
        const int w2 = tid >> 6, s = tid & 63;
        const int row = r0 + w2;
        float l = 0.f;
#pragma unroll
        for (int c = 0; c < 4; ++c) l += pglob[(c * NB + row) * NS + s];
        unsigned n = (unsigned)(row * NS + s);
        unsigned t0u = 0u, t1u = n;
        threefry2x32(0u, 42u, t0u, t1u);
        unsigned bits = t0u ^ t1u;
        float u = (float)(bits >> 9) * (1.0f / 8388608.0f);
        u = fmaxf(u, 1.17549435e-38f);
        float g = -logf(-logf(u));
        float best = l + g;
        int bi = s;
        for (int off = 32; off; off >>= 1) {
            float ov = __shfl_down(best, off);
            int oi = __shfl_down(bi, off);
            if (ov > best || (ov == best && oi < bi)) { best = ov; bi = oi; }
        }
        if (s == 0) o_sh[w2] = bi;
    }
    __syncthreads();

#pragma unroll
    for (int r = 0; r < 2; ++r) {
        const int o = o_sh[r];
        const float2* m0p = (const float2*)(M0 + o * ND);
        const float2* m1p = (const float2*)(M1 + o * ND);
        const float2* xr = xs + r * NP;
        float2* op = (float2*)(out + (r0 + r) * ND);
        float2 xv = xr[tid], m0 = m0p[tid], m1 = m1p[tid];
        float2 rr;
        rr.x = xv.x * m0.x + xv.y * m1.x;
        rr.y = xv.x * m0.y + xv.y * m1.y;
        op[tid] = rr;
    }
}

extern "C" void kernel_launch(void* const* d_in, const int* in_sizes, int n_in,
                              void* d_out, int out_size, void* d_ws, size_t ws_size,
                              hipStream_t stream) {
    const float* x   = (const float*)d_in[0];  // [512,2048]
    const float* amp = (const float*)d_in[1];  // [64,2048]
    const float* ph  = (const float*)d_in[2];  // [64,2048]
    const float* G   = (const float*)d_in[3];  // [64,2,2]
    const float* E   = (const float*)d_in[4];  // [64,64]
    float* out = (float*)d_out;
    float* ws = (float*)d_ws;

    float* M0 = ws + OFF_M0;
    float* M1 = ws + OFF_M1;
    float* Qt = ws + OFF_QT;
    float* R  = ws + OFF_R;
    float* W  = ws + OFF_W;
    float* pp = ws + OFF_PART;

    k_pre <<<64, 256, 0, stream>>>(amp, ph, E, R, W);
    k_MQ  <<<256, 1024, 0, stream>>>(R, W, G, M0, M1, Qt);
    k_logA<<<256, 1024, 0, stream>>>(x, Qt, pp);
    k_logB<<<256, 1024, 0, stream>>>(x, pp, M0, M1, out);
}